// Round 10
// baseline (208.907 us; speedup 1.0000x reference)
//
#include <hip/hip_runtime.h>
#include <hip/hip_bf16.h>

#define DEV __device__ __forceinline__

typedef unsigned short u16;
typedef unsigned int u32;
typedef __attribute__((ext_vector_type(8))) short short8;
typedef __attribute__((ext_vector_type(4))) float f32x4;

DEV u16 f2bf(float f) {
  __hip_bfloat16 h = __float2bfloat16(f);   // RNE; pairs into v_cvt_pk_bf16_f32
  return *(u16*)&h;
}
DEV float bf2f_s(short s) { return __uint_as_float(((u32)(u16)s) << 16); }

#define NB 8
#define NH 6
#define CTOT 192
#define HW 16384
#define QSTR 264   // q/k LDS channel-row stride (u16): 256-px window + 8 pad (16B-mult; 132 dwords -> 2-way max on frag reads)
#define VTS 34     // k3 LDS n-row stride (u16): 32 ch + 2 pad (17 dwords, coprime 32 -> conflict-free frag reads)

// load 10 input floats (8 outputs + 2 halo cols) of one row, zero-padded
DEV void loadrow10(float* d, const float* __restrict__ in, int ar, int c0) {
  const bool rok = (ar >= 0) && (ar < 128);
  const float* rp = in + ar * 128;
  d[0] = (rok && c0 > 0) ? rp[c0 - 1] : 0.0f;
  float4 f0, f1;
  if (rok) { f0 = *(const float4*)(rp + c0); f1 = *(const float4*)(rp + c0 + 4); }
  else { f0 = make_float4(0.f,0.f,0.f,0.f); f1 = f0; }
  d[1] = f0.x; d[2] = f0.y; d[3] = f0.z; d[4] = f0.w;
  d[5] = f1.x; d[6] = f1.y; d[7] = f1.z; d[8] = f1.w;
  d[9] = (rok && (c0 + 8) < 128) ? rp[c0 + 8] : 0.0f;
}

// ---------------------------------------------------------------------------
// K1 (fused, v7): block = (b, head, 4-row stripe, 64-col half) -> 3072 blocks.
// TWO barriers per block total (was 8-16):
//   pass1 (barrier-free): conv q from x over 4 rows (3-slot reg ring) -> q_lds
//   pass2 (barrier-free): conv k,v from y; k -> k_lds; v -> global natural
//                         [b][c][n] layout (coalesced short8, NO transpose)
//   barrier; one MFMA pass over the 256-px window (same verified mapping);
//   gram LDS-reduce (barrier) -> one atomicAdd set.
// Sequential passes share the register ring => lower VGPR => more waves/SIMD.
// ---------------------------------------------------------------------------
__global__ __launch_bounds__(256) void k1_fused(
    const float* __restrict__ x, const float* __restrict__ y,
    const float* __restrict__ wdw,
    u16* __restrict__ vnat, float* __restrict__ gram,
    float* __restrict__ sqq, float* __restrict__ sqk)
{
  const int t   = threadIdx.x;
  const int bx  = blockIdx.x;          // 3072 = b*384 + cg*64 + rg*2 + chp
  const int chp = bx & 1;
  const int rg  = (bx >> 1) & 31;
  const int cg  = (bx >> 6) % 6;       // head
  const int b   = bx / 384;
  const int cl  = t >> 3;              // channel in head 0..31
  const int colgrp = t & 7;
  const int gc  = cg * 32 + cl;
  const int c0  = chp * 64 + colgrp * 8;
  const int r0  = rg * 4;
  const int bh  = b * NH + cg;
  const int l    = t & 63, w = t >> 6;
  const int arow = l & 15;
  const int kq8  = (l >> 4) << 3;

  __shared__ __align__(16) u16 q_lds[32 * QSTR];
  __shared__ __align__(16) u16 k_lds[32 * QSTR];
  __shared__ __align__(16) float gram_lds[1024];

  *(f32x4*)&gram_lds[t * 4] = (f32x4){0.f, 0.f, 0.f, 0.f};

  const float* __restrict__ xin = x + (((size_t)(b * CTOT + gc)) << 14);
  const float* __restrict__ yin = y + (((size_t)(b * CTOT + gc)) << 14);

  // ---- pass 1: q from x ----
  {
    float wq[9];
#pragma unroll
    for (int i = 0; i < 9; ++i) wq[i] = wdw[gc * 9 + i];
    float rb[3][10];
    loadrow10(rb[0], xin, r0 - 1, c0);
    loadrow10(rb[1], xin, r0,     c0);
#pragma unroll
    for (int rl = 0; rl < 4; ++rl) {
      loadrow10(rb[(rl + 2) % 3], xin, r0 + rl + 1, c0);
      float a[8];
#pragma unroll
      for (int j = 0; j < 8; ++j) a[j] = 0.f;
#pragma unroll
      for (int dr = 0; dr < 3; ++dr)
#pragma unroll
        for (int j = 0; j < 8; ++j)
#pragma unroll
          for (int dc = 0; dc < 3; ++dc)
            a[j] = fmaf(wq[dr * 3 + dc], rb[(rl + dr) % 3][j + dc], a[j]);
      short8 p;
#pragma unroll
      for (int j = 0; j < 8; ++j) p[j] = (short)f2bf(a[j]);
      *(short8*)&q_lds[cl * QSTR + rl * 64 + colgrp * 8] = p;
    }
  }

  // ---- pass 2: k,v from y ----
  {
    float wk[9], wv[9];
#pragma unroll
    for (int i = 0; i < 9; ++i) {
      wk[i] = wdw[(CTOT + gc) * 9 + i];
      wv[i] = wdw[(2 * CTOT + gc) * 9 + i];
    }
    float rb[3][10];
    loadrow10(rb[0], yin, r0 - 1, c0);
    loadrow10(rb[1], yin, r0,     c0);
    u16* __restrict__ vout = vnat + (((size_t)(b * CTOT + gc)) << 14);
#pragma unroll
    for (int rl = 0; rl < 4; ++rl) {
      loadrow10(rb[(rl + 2) % 3], yin, r0 + rl + 1, c0);
      float ak[8], av[8];
#pragma unroll
      for (int j = 0; j < 8; ++j) { ak[j] = 0.f; av[j] = 0.f; }
#pragma unroll
      for (int dr = 0; dr < 3; ++dr)
#pragma unroll
        for (int j = 0; j < 8; ++j)
#pragma unroll
          for (int dc = 0; dc < 3; ++dc) {
            ak[j] = fmaf(wk[dr * 3 + dc], rb[(rl + dr) % 3][j + dc], ak[j]);
            av[j] = fmaf(wv[dr * 3 + dc], rb[(rl + dr) % 3][j + dc], av[j]);
          }
      short8 pk, pv;
#pragma unroll
      for (int j = 0; j < 8; ++j) { pk[j] = (short)f2bf(ak[j]); pv[j] = (short)f2bf(av[j]); }
      *(short8*)&k_lds[cl * QSTR + rl * 64 + colgrp * 8] = pk;
      *(short8*)(vout + (r0 + rl) * 128 + c0) = pv;   // natural [b][c][n], coalesced
    }
  }

  __syncthreads();

  // ---- MFMA pass: gram over the 256-px window; wave w owns px w*64..+63 ----
  f32x4 acc[2][2] = {};
  float sq[2] = {0.f, 0.f}, sk2[2] = {0.f, 0.f};
  short8 a2[2][2], b2[2][2];   // [tc][kk]
#pragma unroll
  for (int tc = 0; tc < 2; ++tc)
#pragma unroll
    for (int kk = 0; kk < 2; ++kk) {
      const int off = w * 64 + kk * 32 + kq8;
      a2[tc][kk] = *(const short8*)&q_lds[(tc * 16 + arow) * QSTR + off];
      b2[tc][kk] = *(const short8*)&k_lds[(tc * 16 + arow) * QSTR + off];
    }
#pragma unroll
  for (int tc = 0; tc < 2; ++tc)
#pragma unroll
    for (int kk = 0; kk < 2; ++kk)
#pragma unroll
      for (int j = 0; j < 8; ++j) {
        float fa = bf2f_s(a2[tc][kk][j]); sq[tc] = fmaf(fa, fa, sq[tc]);
        float fb = bf2f_s(b2[tc][kk][j]); sk2[tc] = fmaf(fb, fb, sk2[tc]);
      }
#pragma unroll
  for (int kk = 0; kk < 2; ++kk)
#pragma unroll
    for (int tc = 0; tc < 2; ++tc)
#pragma unroll
      for (int td = 0; td < 2; ++td)
        acc[tc][td] = __builtin_amdgcn_mfma_f32_16x16x32_bf16(a2[tc][kk], b2[td][kk], acc[tc][td], 0, 0, 0);

  // block-level gram reduction in LDS, then one global atomicAdd per element
#pragma unroll
  for (int tc = 0; tc < 2; ++tc)
#pragma unroll
    for (int td = 0; td < 2; ++td)
#pragma unroll
      for (int r2 = 0; r2 < 4; ++r2) {
        int c = tc * 16 + (l >> 4) * 4 + r2;
        int d = td * 16 + arow;
        atomicAdd(&gram_lds[c * 32 + d], acc[tc][td][r2]);
      }
  __syncthreads();
#pragma unroll
  for (int i = 0; i < 4; ++i)
    atomicAdd(gram + (size_t)bh * 1024 + t * 4 + i, gram_lds[t * 4 + i]);

#pragma unroll
  for (int tc = 0; tc < 2; ++tc) {
    sq[tc]  += __shfl_xor(sq[tc], 16);
    sq[tc]  += __shfl_xor(sq[tc], 32);
    sk2[tc] += __shfl_xor(sk2[tc], 16);
    sk2[tc] += __shfl_xor(sk2[tc], 32);
  }
  if ((l >> 4) == 0) {
#pragma unroll
    for (int tc = 0; tc < 2; ++tc) {
      atomicAdd(sqq + bh * 32 + tc * 16 + arow, sq[tc]);
      atomicAdd(sqk + bh * 32 + tc * 16 + arow, sk2[tc]);
    }
  }
}

// ---------------------------------------------------------------------------
// K2b: logits = gram/(|q||k|)*temp, row-softmax, fold 1x1 proj:
//   W2[b][o][h*32+d] = sum_c wp[o][h*32+c] * A[c][d]  (bf16 out)
// ---------------------------------------------------------------------------
__global__ __launch_bounds__(256) void k2b_w2(
    const float* __restrict__ gram, const float* __restrict__ sqq,
    const float* __restrict__ sqk, const float* __restrict__ wp,
    const float* __restrict__ temp, u16* __restrict__ W2)
{
  __shared__ float Ls[32][33];
  __shared__ float As[32][33];
  __shared__ float wl[192 * 32];
  __shared__ float nq[32], nk[32];
  const int t = threadIdx.x;
  const int bh = blockIdx.x, b = bh / 6, h = bh % 6;
  const float tmp = temp[h];
  if (t < 32) nq[t] = fmaxf(sqrtf(sqq[bh * 32 + t]), 1e-12f);
  else if (t < 64) nk[t - 32] = fmaxf(sqrtf(sqk[bh * 32 + t - 32]), 1e-12f);
  __syncthreads();
#pragma unroll
  for (int i = 0; i < 4; ++i) {
    int idx = i * 256 + t, c = idx >> 5, d = idx & 31;
    Ls[c][d] = gram[(size_t)bh * 1024 + idx] / (nq[c] * nk[d]) * tmp;
  }
  __syncthreads();
  if (t < 32) {
    float m = -1e30f;
#pragma unroll
    for (int d = 0; d < 32; ++d) m = fmaxf(m, Ls[t][d]);
    float s = 0.f;
#pragma unroll
    for (int d = 0; d < 32; ++d) s += expf(Ls[t][d] - m);
    float inv = 1.0f / s;
#pragma unroll
    for (int d = 0; d < 32; ++d) As[t][d] = expf(Ls[t][d] - m) * inv;
  }
  for (int i = 0; i < 24; ++i) {
    int idx = i * 256 + t, o = idx >> 5, c = idx & 31;
    wl[idx] = wp[o * 192 + h * 32 + c];
  }
  __syncthreads();
  for (int i = 0; i < 24; ++i) {
    int idx = i * 256 + t, o = idx >> 5, d = idx & 31;
    float a = 0.f;
#pragma unroll
    for (int c = 0; c < 32; ++c) a = fmaf(wl[o * 32 + c], As[c][d], a);
    W2[((size_t)(b * 192 + o)) * 192 + h * 32 + d] = f2bf(a);
  }
}

// ---------------------------------------------------------------------------
// K3 (v7): out[b][o][n] = sum_c W2[b][o][c] * v[b][c][n], MFMA 16x16x32 bf16.
// v is in natural [b][c][n] layout; per ks-step (= head), stage the 32x128
// tile into LDS [n][VTS] (transpose) with coalesced global reads; fragment
// reads are conflict-free (17-dword row stride, coprime with 32 banks).
// ---------------------------------------------------------------------------
__global__ __launch_bounds__(256) void k3_gemm(
    const u16* __restrict__ W2, const u16* __restrict__ vnat,
    float* __restrict__ out)
{
  __shared__ __align__(16) u16 b_tile[128 * VTS];
  const int t = threadIdx.x, l = t & 63, w = t >> 6;
  const int bx = blockIdx.x;
  const int b  = bx >> 7, nb = bx & 127;
  const int arow = l & 15;
  const int kq8  = (l >> 4) * 8;
  const u16* w2b = W2 + (size_t)b * 192 * 192;
  const u16* vb  = vnat + ((size_t)b * CTOT) * HW;
  const int n0 = nb * 128;

  f32x4 acc[12][2] = {};

  for (int ks = 0; ks < 6; ++ks) {
    if (ks > 0) __syncthreads();           // all waves done reading b_tile
    // stage v[ks*32 .. +31][n0 .. n0+127] -> b_tile[n][ch] (2 rounds)
#pragma unroll
    for (int r2 = 0; r2 < 2; ++r2) {
      const int ch   = (t >> 4) + r2 * 16;
      const int nseg = (t & 15) * 8;
      short8 vv = *(const short8*)(vb + (size_t)(ks * 32 + ch) * HW + n0 + nseg);
#pragma unroll
      for (int j = 0; j < 8; ++j) b_tile[(nseg + j) * VTS + ch] = (u16)vv[j];
    }
    __syncthreads();

    short8 bf[2];
#pragma unroll
    for (int nt = 0; nt < 2; ++nt)
      bf[nt] = *(const short8*)&b_tile[(w * 32 + nt * 16 + arow) * VTS + kq8];
#pragma unroll
    for (int ot = 0; ot < 12; ++ot) {
      short8 af = *(const short8*)(w2b + (size_t)(ot * 16 + arow) * 192 + ks * 32 + kq8);
#pragma unroll
      for (int nt = 0; nt < 2; ++nt)
        acc[ot][nt] = __builtin_amdgcn_mfma_f32_16x16x32_bf16(af, bf[nt], acc[ot][nt], 0, 0, 0);
    }
  }

  float* ob = out + ((size_t)b * 192) * 16384;
#pragma unroll
  for (int ot = 0; ot < 12; ++ot)
#pragma unroll
    for (int nt = 0; nt < 2; ++nt)
#pragma unroll
      for (int rr = 0; rr < 4; ++rr) {
        int o = ot * 16 + (l >> 4) * 4 + rr;
        int n = n0 + w * 32 + nt * 16 + arow;
        ob[(size_t)o * 16384 + n] = acc[ot][nt][rr];
      }
}

// ---------------------------------------------------------------------------
extern "C" void kernel_launch(void* const* d_in, const int* in_sizes, int n_in,
                              void* d_out, int out_size, void* d_ws, size_t ws_size,
                              hipStream_t stream)
{
  const float* x    = (const float*)d_in[0];
  const float* y    = (const float*)d_in[1];
  const float* wdw  = (const float*)d_in[2];
  const float* wp   = (const float*)d_in[3];
  const float* temp = (const float*)d_in[4];

  char* ws = (char*)d_ws;
  const size_t VT = (size_t)NB * HW * CTOT * 2;   // 50,331,648 bytes
  u16*   vnat = (u16*)(ws);
  float* gram = (float*)(ws + VT);                       // 48*1024*4 = 196608
  float* sqq  = (float*)(ws + VT + 196608);              // 6144
  float* sqk  = (float*)(ws + VT + 196608 + 6144);       // 6144
  u16*   W2   = (u16*)(ws + VT + 196608 + 12288);        // 8*192*192*2
  float* out  = (float*)d_out;

  hipMemsetAsync(ws + VT, 0, 208896, stream);
  k1_fused<<<3072, 256, 0, stream>>>(x, y, wdw, vnat, gram, sqq, sqk);
  k2b_w2<<<48, 256, 0, stream>>>(gram, sqq, sqk, wp, temp, W2);
  k3_gemm<<<1024, 256, 0, stream>>>(W2, vnat, out);
}

// Round 11
// 174.547 us; speedup vs baseline: 1.1968x; 1.1968x over previous
//
#include <hip/hip_runtime.h>
#include <hip/hip_bf16.h>

#define DEV __device__ __forceinline__

typedef unsigned short u16;
typedef unsigned int u32;
typedef __attribute__((ext_vector_type(8))) short short8;
typedef __attribute__((ext_vector_type(4))) float f32x4;

DEV u16 f2bf(float f) {
  __hip_bfloat16 h = __float2bfloat16(f);   // RNE
  return *(u16*)&h;
}
DEV float bf2f_s(short s) { return __uint_as_float(((u32)(u16)s) << 16); }

#define NB 8
#define NH 6
#define CTOT 192
#define HW 16384
#define VTS 34     // k3 LDS n-row stride (u16): 17 dwords, coprime 32 banks

// ---------------------------------------------------------------------------
// KCONV: depthwise 3x3 conv, un-fused, streaming, barrier-free, LDS-free.
// wave = one (class, b, channel, 32-row stripe). lane owns px {2*lane,2*lane+1}
// of each 128-px row: float2 row loads (512B/wave, perfectly coalesced),
// column neighbors via 2 shfl per row, 3(+1)-slot register row ring with
// static indexing (unroll 4). kv-waves compute k AND v from one y read.
// tasks: 0..6143 = q (x), 6144..12287 = k+v (y). 3072 blocks x 4 waves.
// ---------------------------------------------------------------------------
__global__ __launch_bounds__(256) void kconv(
    const float* __restrict__ x, const float* __restrict__ y,
    const float* __restrict__ wdw,
    u16* __restrict__ qws, u16* __restrict__ kws, u16* __restrict__ vws)
{
  const int t = threadIdx.x, lane = t & 63, w = t >> 6;
  int task = blockIdx.x * 4 + w;
  const int iskv = (task >= 6144) ? 1 : 0;
  if (iskv) task -= 6144;
  const int b   = task / 768;
  const int rem = task - b * 768;
  const int gc  = rem >> 2;            // channel 0..191
  const int rg  = rem & 3;             // 32-row stripe
  const int r0  = rg * 32;

  const float* __restrict__ in =
      (iskv ? y : x) + (((size_t)(b * CTOT + gc)) << 14);

  float w0[9], w1[9];
  if (!iskv) {
#pragma unroll
    for (int i = 0; i < 9; ++i) w0[i] = wdw[gc * 9 + i];
  } else {
#pragma unroll
    for (int i = 0; i < 9; ++i) {
      w0[i] = wdw[(CTOT + gc) * 9 + i];       // k
      w1[i] = wdw[(2 * CTOT + gc) * 9 + i];   // v
    }
  }

  u16* __restrict__ out0 =
      (iskv ? kws : qws) + (((size_t)(b * CTOT + gc)) << 14);
  u16* __restrict__ out1 = vws + (((size_t)(b * CTOT + gc)) << 14);

  // raw row load (float2/lane), zero outside image
  #define LOADRAW(ar) ((ar) >= 0 && (ar) < 128 \
      ? *(const float2*)(in + (ar) * 128 + lane * 2) \
      : make_float2(0.f, 0.f))
  // shuffle-complete a row: (left=px2i-1, a0=px2i, a1=px2i+1, right=px2i+2)
  #define SHUF(v, dst) { \
      float lf = __shfl_up((v).y, 1);  if (lane == 0)  lf = 0.f; \
      float rt = __shfl_down((v).x, 1); if (lane == 63) rt = 0.f; \
      (dst) = make_float4(lf, (v).x, (v).y, rt); }

  float4 ring[4];            // shuffled rows; slot(ar) = (ar - r0 + 1) & 3
  float2 raw[2];
  { float2 v = LOADRAW(r0 - 1); SHUF(v, ring[0]); }
  { float2 v = LOADRAW(r0);     SHUF(v, ring[1]); }
  raw[1] = LOADRAW(r0 + 1);

  for (int r8 = 0; r8 < 8; ++r8) {
#pragma unroll
    for (int j = 0; j < 4; ++j) {
      const int r = r0 + r8 * 4 + j;
      raw[j & 1] = LOADRAW(r + 2);                 // prefetch (used next iter)
      SHUF(raw[(j + 1) & 1], ring[(j + 2) & 3]);   // complete row r+1
      const float4 rm = ring[j & 3];               // row r-1
      const float4 rc = ring[(j + 1) & 3];         // row r
      const float4 rp = ring[(j + 2) & 3];         // row r+1

      float o0, o1;
      o0 = w0[0] * rm.x; o0 = fmaf(w0[1], rm.y, o0); o0 = fmaf(w0[2], rm.z, o0);
      o0 = fmaf(w0[3], rc.x, o0); o0 = fmaf(w0[4], rc.y, o0); o0 = fmaf(w0[5], rc.z, o0);
      o0 = fmaf(w0[6], rp.x, o0); o0 = fmaf(w0[7], rp.y, o0); o0 = fmaf(w0[8], rp.z, o0);
      o1 = w0[0] * rm.y; o1 = fmaf(w0[1], rm.z, o1); o1 = fmaf(w0[2], rm.w, o1);
      o1 = fmaf(w0[3], rc.y, o1); o1 = fmaf(w0[4], rc.z, o1); o1 = fmaf(w0[5], rc.w, o1);
      o1 = fmaf(w0[6], rp.y, o1); o1 = fmaf(w0[7], rp.z, o1); o1 = fmaf(w0[8], rp.w, o1);
      ((u32*)(out0 + r * 128))[lane] = ((u32)f2bf(o1) << 16) | (u32)f2bf(o0);

      if (iskv) {
        float v0, v1;
        v0 = w1[0] * rm.x; v0 = fmaf(w1[1], rm.y, v0); v0 = fmaf(w1[2], rm.z, v0);
        v0 = fmaf(w1[3], rc.x, v0); v0 = fmaf(w1[4], rc.y, v0); v0 = fmaf(w1[5], rc.z, v0);
        v0 = fmaf(w1[6], rp.x, v0); v0 = fmaf(w1[7], rp.y, v0); v0 = fmaf(w1[8], rp.z, v0);
        v1 = w1[0] * rm.y; v1 = fmaf(w1[1], rm.z, v1); v1 = fmaf(w1[2], rm.w, v1);
        v1 = fmaf(w1[3], rc.y, v1); v1 = fmaf(w1[4], rc.z, v1); v1 = fmaf(w1[5], rc.w, v1);
        v1 = fmaf(w1[6], rp.y, v1); v1 = fmaf(w1[7], rp.z, v1); v1 = fmaf(w1[8], rp.w, v1);
        ((u32*)(out1 + r * 128))[lane] = ((u32)f2bf(v1) << 16) | (u32)f2bf(v0);
      }
    }
  }
  #undef LOADRAW
  #undef SHUF
}

// ---------------------------------------------------------------------------
// K2a (verified R3): per (b,head) gram[c][d] = sum_n q[c][n]*k[d][n] via MFMA,
// plus sum-of-squares. grid 48x16 p-tiles, f32-atomic partials (pre-zeroed).
// ---------------------------------------------------------------------------
__global__ __launch_bounds__(256) void k2a_gram(
    const u16* __restrict__ qws, const u16* __restrict__ kws,
    float* __restrict__ gram, float* __restrict__ sqq, float* __restrict__ sqk)
{
  const int t = threadIdx.x, l = t & 63, w = t >> 6;
  const int bh = blockIdx.x >> 4, tile = blockIdx.x & 15;
  const int p0 = tile * 1024 + w * 256;
  const u16* qb = qws + (((size_t)bh) << 19);
  const u16* kb = kws + (((size_t)bh) << 19);
  const int row = l & 15;
  const int kq  = (l >> 4) * 8;

  f32x4 acc[2][2] = {};
  float sq[2] = {0.f, 0.f}, sk[2] = {0.f, 0.f};

  for (int ks = 0; ks < 8; ++ks) {
    const int p = p0 + ks * 32 + kq;
    short8 av[2], bv[2];
#pragma unroll
    for (int tc = 0; tc < 2; ++tc) {
      av[tc] = *(const short8*)(qb + (((size_t)(tc * 16 + row)) << 14) + p);
      bv[tc] = *(const short8*)(kb + (((size_t)(tc * 16 + row)) << 14) + p);
    }
#pragma unroll
    for (int tc = 0; tc < 2; ++tc) {
#pragma unroll
      for (int j = 0; j < 8; ++j) {
        float fa = bf2f_s(av[tc][j]); sq[tc] = fmaf(fa, fa, sq[tc]);
        float fb = bf2f_s(bv[tc][j]); sk[tc] = fmaf(fb, fb, sk[tc]);
      }
    }
#pragma unroll
    for (int tc = 0; tc < 2; ++tc)
#pragma unroll
      for (int td = 0; td < 2; ++td)
        acc[tc][td] = __builtin_amdgcn_mfma_f32_16x16x32_bf16(av[tc], bv[td], acc[tc][td], 0, 0, 0);
  }

#pragma unroll
  for (int tc = 0; tc < 2; ++tc)
#pragma unroll
    for (int td = 0; td < 2; ++td)
#pragma unroll
      for (int rr = 0; rr < 4; ++rr) {
        int c = tc * 16 + (l >> 4) * 4 + rr;
        int d = td * 16 + row;
        atomicAdd(gram + (size_t)bh * 1024 + c * 32 + d, acc[tc][td][rr]);
      }

#pragma unroll
  for (int tc = 0; tc < 2; ++tc) {
    sq[tc] += __shfl_xor(sq[tc], 16);
    sq[tc] += __shfl_xor(sq[tc], 32);
    sk[tc] += __shfl_xor(sk[tc], 16);
    sk[tc] += __shfl_xor(sk[tc], 32);
  }
  if ((l >> 4) == 0) {
#pragma unroll
    for (int tc = 0; tc < 2; ++tc) {
      atomicAdd(sqq + bh * 32 + tc * 16 + row, sq[tc]);
      atomicAdd(sqk + bh * 32 + tc * 16 + row, sk[tc]);
    }
  }
}

// ---------------------------------------------------------------------------
// K2b: logits = gram/(|q||k|)*temp, row-softmax, fold 1x1 proj:
//   W2[b][o][h*32+d] = sum_c wp[o][h*32+c] * A[c][d]  (bf16 out)
// ---------------------------------------------------------------------------
__global__ __launch_bounds__(256) void k2b_w2(
    const float* __restrict__ gram, const float* __restrict__ sqq,
    const float* __restrict__ sqk, const float* __restrict__ wp,
    const float* __restrict__ temp, u16* __restrict__ W2)
{
  __shared__ float Ls[32][33];
  __shared__ float As[32][33];
  __shared__ float wl[192 * 32];
  __shared__ float nq[32], nk[32];
  const int t = threadIdx.x;
  const int bh = blockIdx.x, b = bh / 6, h = bh % 6;
  const float tmp = temp[h];
  if (t < 32) nq[t] = fmaxf(sqrtf(sqq[bh * 32 + t]), 1e-12f);
  else if (t < 64) nk[t - 32] = fmaxf(sqrtf(sqk[bh * 32 + t - 32]), 1e-12f);
  __syncthreads();
#pragma unroll
  for (int i = 0; i < 4; ++i) {
    int idx = i * 256 + t, c = idx >> 5, d = idx & 31;
    Ls[c][d] = gram[(size_t)bh * 1024 + idx] / (nq[c] * nk[d]) * tmp;
  }
  __syncthreads();
  if (t < 32) {
    float m = -1e30f;
#pragma unroll
    for (int d = 0; d < 32; ++d) m = fmaxf(m, Ls[t][d]);
    float s = 0.f;
#pragma unroll
    for (int d = 0; d < 32; ++d) s += expf(Ls[t][d] - m);
    float inv = 1.0f / s;
#pragma unroll
    for (int d = 0; d < 32; ++d) As[t][d] = expf(Ls[t][d] - m) * inv;
  }
  for (int i = 0; i < 24; ++i) {
    int idx = i * 256 + t, o = idx >> 5, c = idx & 31;
    wl[idx] = wp[o * 192 + h * 32 + c];
  }
  __syncthreads();
  for (int i = 0; i < 24; ++i) {
    int idx = i * 256 + t, o = idx >> 5, d = idx & 31;
    float a = 0.f;
#pragma unroll
    for (int c = 0; c < 32; ++c) a = fmaf(wl[o * 32 + c], As[c][d], a);
    W2[((size_t)(b * 192 + o)) * 192 + h * 32 + d] = f2bf(a);
  }
}

// ---------------------------------------------------------------------------
// K3: out[b][o][n] = sum_c W2[b][o][c] * v[b][c][n], MFMA 16x16x32 bf16.
// v in natural [b][c][n]; per ks-step stage 32x128 tile -> LDS transpose.
// Epilogue: LDS-transpose C so global stores are contiguous float4 runs
// (was 64B-granule scatter). og loop fully unrolled (static acc indexing).
// ---------------------------------------------------------------------------
__global__ __launch_bounds__(256) void k3_gemm(
    const u16* __restrict__ W2, const u16* __restrict__ vnat,
    float* __restrict__ out)
{
  __shared__ __align__(16) u16 b_tile[128 * VTS];
  __shared__ __align__(16) float cout[32 * 132];
  const int t = threadIdx.x, l = t & 63, w = t >> 6;
  const int bx = blockIdx.x;
  const int b  = bx >> 7, nb = bx & 127;
  const int arow = l & 15;
  const int kq8  = (l >> 4) * 8;
  const u16* w2b = W2 + (size_t)b * 192 * 192;
  const u16* vb  = vnat + ((size_t)b * CTOT) * HW;
  const int n0 = nb * 128;

  f32x4 acc[12][2] = {};

  for (int ks = 0; ks < 6; ++ks) {
    if (ks > 0) __syncthreads();
#pragma unroll
    for (int r2 = 0; r2 < 2; ++r2) {
      const int ch   = (t >> 4) + r2 * 16;
      const int nseg = (t & 15) * 8;
      short8 vv = *(const short8*)(vb + (size_t)(ks * 32 + ch) * HW + n0 + nseg);
#pragma unroll
      for (int j = 0; j < 8; ++j) b_tile[(nseg + j) * VTS + ch] = (u16)vv[j];
    }
    __syncthreads();

    short8 bf[2];
#pragma unroll
    for (int nt = 0; nt < 2; ++nt)
      bf[nt] = *(const short8*)&b_tile[(w * 32 + nt * 16 + arow) * VTS + kq8];
#pragma unroll
    for (int ot = 0; ot < 12; ++ot) {
      short8 af = *(const short8*)(w2b + (size_t)(ot * 16 + arow) * 192 + ks * 32 + kq8);
#pragma unroll
      for (int nt = 0; nt < 2; ++nt)
        acc[ot][nt] = __builtin_amdgcn_mfma_f32_16x16x32_bf16(af, bf[nt], acc[ot][nt], 0, 0, 0);
    }
  }

  float* __restrict__ ob = out + ((size_t)b * 192) * 16384;
#pragma unroll
  for (int og = 0; og < 6; ++og) {
    __syncthreads();
#pragma unroll
    for (int oi = 0; oi < 2; ++oi) {
#pragma unroll
      for (int nt = 0; nt < 2; ++nt)
#pragma unroll
        for (int rr = 0; rr < 4; ++rr) {
          const int o_l = oi * 16 + (l >> 4) * 4 + rr;
          const int n_l = w * 32 + nt * 16 + (l & 15);
          cout[o_l * 132 + n_l] = acc[og * 2 + oi][nt][rr];
        }
    }
    __syncthreads();
    const int o_l = t >> 3;
    const int o   = og * 32 + o_l;
#pragma unroll
    for (int c = 0; c < 4; ++c) {
      const int n = (t & 7) * 4 + c * 32;
      float4 v4;
      v4.x = cout[o_l * 132 + n + 0];
      v4.y = cout[o_l * 132 + n + 1];
      v4.z = cout[o_l * 132 + n + 2];
      v4.w = cout[o_l * 132 + n + 3];
      *(float4*)(ob + (size_t)o * 16384 + n0 + n) = v4;
    }
  }
}

// ---------------------------------------------------------------------------
extern "C" void kernel_launch(void* const* d_in, const int* in_sizes, int n_in,
                              void* d_out, int out_size, void* d_ws, size_t ws_size,
                              hipStream_t stream)
{
  const float* x    = (const float*)d_in[0];
  const float* y    = (const float*)d_in[1];
  const float* wdw  = (const float*)d_in[2];
  const float* wp   = (const float*)d_in[3];
  const float* temp = (const float*)d_in[4];

  char* ws = (char*)d_ws;
  const size_t QK = (size_t)NB * CTOT * HW * 2;   // 50,331,648 bytes per tensor
  u16*   qws  = (u16*)(ws);
  u16*   kws  = (u16*)(ws + QK);
  u16*   vws  = (u16*)(ws + 2 * QK);
  float* gram = (float*)(ws + 3 * QK);                  // 196608
  float* sqq  = (float*)(ws + 3 * QK + 196608);         // 6144
  float* sqk  = (float*)(ws + 3 * QK + 196608 + 6144);  // 6144
  u16*   W2   = (u16*)(ws + 3 * QK + 196608 + 12288);   // 8*192*192*2
  float* out  = (float*)d_out;

  hipMemsetAsync(ws + 3 * QK, 0, 208896, stream);
  kconv<<<3072, 256, 0, stream>>>(x, y, wdw, qws, kws, vws);
  k2a_gram<<<768, 256, 0, stream>>>(qws, kws, gram, sqq, sqk);
  k2b_w2<<<48, 256, 0, stream>>>(gram, sqq, sqk, wp, temp, W2);
  k3_gemm<<<1024, 256, 0, stream>>>(W2, vws, out);
}

// Round 12
// 172.418 us; speedup vs baseline: 1.2116x; 1.0124x over previous
//
#include <hip/hip_runtime.h>
#include <hip/hip_bf16.h>

#define DEV __device__ __forceinline__

typedef unsigned short u16;
typedef unsigned int u32;
typedef __attribute__((ext_vector_type(8))) short short8;
typedef __attribute__((ext_vector_type(4))) float f32x4;

DEV u16 f2bf(float f) {
  __hip_bfloat16 h = __float2bfloat16(f);   // RNE
  return *(u16*)&h;
}
DEV float bf2f_s(short s) { return __uint_as_float(((u32)(u16)s) << 16); }

#define NB 8
#define NH 6
#define CTOT 192
#define HW 16384
#define VTS 34     // k3 LDS n-row stride (u16): 17 dwords, coprime 32 banks

// ---------------------------------------------------------------------------
// KCONV v2: depthwise 3x3 conv, streaming, barrier-free, LDS-free.
// wave = (class, b, channel, 32-row stripe); lane owns px {2i,2i+1}.
// vs R11: 2-row groups with a 2-deep raw prefetch ring (m0,m1 issued one full
// group before their SHUF/conv use -> ~200-400cy slack, 4 loads in flight)
// and carried shuffled rows (1 SHUF per row). Targets the 75% latency stall
// (VALUBusy was 25%) while keeping VGPR < 64 for 8 waves/SIMD.
// ---------------------------------------------------------------------------
__global__ __launch_bounds__(256) void kconv(
    const float* __restrict__ x, const float* __restrict__ y,
    const float* __restrict__ wdw,
    u16* __restrict__ qws, u16* __restrict__ kws, u16* __restrict__ vws)
{
  const int t = threadIdx.x, lane = t & 63, w = t >> 6;
  int task = blockIdx.x * 4 + w;
  const int iskv = (task >= 6144) ? 1 : 0;
  if (iskv) task -= 6144;
  const int b   = task / 768;
  const int rem = task - b * 768;
  const int gc  = rem >> 2;            // channel 0..191
  const int rg  = rem & 3;             // 32-row stripe
  const int r0  = rg * 32;

  const float* __restrict__ in =
      (iskv ? y : x) + (((size_t)(b * CTOT + gc)) << 14);

  float w0[9], w1[9];
  if (!iskv) {
#pragma unroll
    for (int i = 0; i < 9; ++i) w0[i] = wdw[gc * 9 + i];
  } else {
#pragma unroll
    for (int i = 0; i < 9; ++i) {
      w0[i] = wdw[(CTOT + gc) * 9 + i];       // k
      w1[i] = wdw[(2 * CTOT + gc) * 9 + i];   // v
    }
  }

  u16* __restrict__ out0 =
      (iskv ? kws : qws) + (((size_t)(b * CTOT + gc)) << 14);
  u16* __restrict__ out1 = vws + (((size_t)(b * CTOT + gc)) << 14);

  #define LOADRAW(ar) ((ar) >= 0 && (ar) < 128 \
      ? *(const float2*)(in + (ar) * 128 + lane * 2) \
      : make_float2(0.f, 0.f))
  #define SHUF(v, dst) { \
      float lf = __shfl_up((v).y, 1);   if (lane == 0)  lf = 0.f; \
      float rt = __shfl_down((v).x, 1); if (lane == 63) rt = 0.f; \
      (dst) = make_float4(lf, (v).x, (v).y, rt); }
  // rows: ra=r-1, rb=r, rc=r+1 (shuffled). out px0=(x,y,z) taps, px1=(y,z,w).
  #define CONVROW(r, ra, rb, rc) { \
      float o0, o1; \
      o0 = w0[0] * (ra).x; o0 = fmaf(w0[1], (ra).y, o0); o0 = fmaf(w0[2], (ra).z, o0); \
      o0 = fmaf(w0[3], (rb).x, o0); o0 = fmaf(w0[4], (rb).y, o0); o0 = fmaf(w0[5], (rb).z, o0); \
      o0 = fmaf(w0[6], (rc).x, o0); o0 = fmaf(w0[7], (rc).y, o0); o0 = fmaf(w0[8], (rc).z, o0); \
      o1 = w0[0] * (ra).y; o1 = fmaf(w0[1], (ra).z, o1); o1 = fmaf(w0[2], (ra).w, o1); \
      o1 = fmaf(w0[3], (rb).y, o1); o1 = fmaf(w0[4], (rb).z, o1); o1 = fmaf(w0[5], (rb).w, o1); \
      o1 = fmaf(w0[6], (rc).y, o1); o1 = fmaf(w0[7], (rc).z, o1); o1 = fmaf(w0[8], (rc).w, o1); \
      ((u32*)(out0 + (r) * 128))[lane] = ((u32)f2bf(o1) << 16) | (u32)f2bf(o0); \
      if (iskv) { \
        float v0, v1; \
        v0 = w1[0] * (ra).x; v0 = fmaf(w1[1], (ra).y, v0); v0 = fmaf(w1[2], (ra).z, v0); \
        v0 = fmaf(w1[3], (rb).x, v0); v0 = fmaf(w1[4], (rb).y, v0); v0 = fmaf(w1[5], (rb).z, v0); \
        v0 = fmaf(w1[6], (rc).x, v0); v0 = fmaf(w1[7], (rc).y, v0); v0 = fmaf(w1[8], (rc).z, v0); \
        v1 = w1[0] * (ra).y; v1 = fmaf(w1[1], (ra).z, v1); v1 = fmaf(w1[2], (ra).w, v1); \
        v1 = fmaf(w1[3], (rb).y, v1); v1 = fmaf(w1[4], (rb).z, v1); v1 = fmaf(w1[5], (rb).w, v1); \
        v1 = fmaf(w1[6], (rc).y, v1); v1 = fmaf(w1[7], (rc).z, v1); v1 = fmaf(w1[8], (rc).w, v1); \
        ((u32*)(out1 + (r) * 128))[lane] = ((u32)f2bf(v1) << 16) | (u32)f2bf(v0); \
      } }

  float4 s0, s1, s2, s3;
  float2 n0, n1, m0 = make_float2(0.f, 0.f), m1 = make_float2(0.f, 0.f);
  { float2 v = LOADRAW(r0 - 1); SHUF(v, s0); }
  { float2 v = LOADRAW(r0);     SHUF(v, s1); }
  n0 = LOADRAW(r0 + 1);
  n1 = LOADRAW(r0 + 2);

#pragma unroll 4
  for (int g = 0; g < 16; ++g) {
    const int R = r0 + g * 2;
    if (g < 15) {                 // prefetch rows R+3, R+4 (used next group)
      m0 = LOADRAW(R + 3);
      m1 = LOADRAW(R + 4);
    }
    SHUF(n0, s2);                 // rows R+1, R+2 (loaded last group)
    SHUF(n1, s3);
    CONVROW(R,     s0, s1, s2);
    CONVROW(R + 1, s1, s2, s3);
    s0 = s2; s1 = s3;
    n0 = m0; n1 = m1;
  }
  #undef LOADRAW
  #undef SHUF
  #undef CONVROW
}

// ---------------------------------------------------------------------------
// K2a (verified R3): per (b,head) gram[c][d] = sum_n q[c][n]*k[d][n] via MFMA,
// plus sum-of-squares. grid 48x16 p-tiles, f32-atomic partials (pre-zeroed).
// ---------------------------------------------------------------------------
__global__ __launch_bounds__(256) void k2a_gram(
    const u16* __restrict__ qws, const u16* __restrict__ kws,
    float* __restrict__ gram, float* __restrict__ sqq, float* __restrict__ sqk)
{
  const int t = threadIdx.x, l = t & 63, w = t >> 6;
  const int bh = blockIdx.x >> 4, tile = blockIdx.x & 15;
  const int p0 = tile * 1024 + w * 256;
  const u16* qb = qws + (((size_t)bh) << 19);
  const u16* kb = kws + (((size_t)bh) << 19);
  const int row = l & 15;
  const int kq  = (l >> 4) * 8;

  f32x4 acc[2][2] = {};
  float sq[2] = {0.f, 0.f}, sk[2] = {0.f, 0.f};

  for (int ks = 0; ks < 8; ++ks) {
    const int p = p0 + ks * 32 + kq;
    short8 av[2], bv[2];
#pragma unroll
    for (int tc = 0; tc < 2; ++tc) {
      av[tc] = *(const short8*)(qb + (((size_t)(tc * 16 + row)) << 14) + p);
      bv[tc] = *(const short8*)(kb + (((size_t)(tc * 16 + row)) << 14) + p);
    }
#pragma unroll
    for (int tc = 0; tc < 2; ++tc) {
#pragma unroll
      for (int j = 0; j < 8; ++j) {
        float fa = bf2f_s(av[tc][j]); sq[tc] = fmaf(fa, fa, sq[tc]);
        float fb = bf2f_s(bv[tc][j]); sk[tc] = fmaf(fb, fb, sk[tc]);
      }
    }
#pragma unroll
    for (int tc = 0; tc < 2; ++tc)
#pragma unroll
      for (int td = 0; td < 2; ++td)
        acc[tc][td] = __builtin_amdgcn_mfma_f32_16x16x32_bf16(av[tc], bv[td], acc[tc][td], 0, 0, 0);
  }

#pragma unroll
  for (int tc = 0; tc < 2; ++tc)
#pragma unroll
    for (int td = 0; td < 2; ++td)
#pragma unroll
      for (int rr = 0; rr < 4; ++rr) {
        int c = tc * 16 + (l >> 4) * 4 + rr;
        int d = td * 16 + row;
        atomicAdd(gram + (size_t)bh * 1024 + c * 32 + d, acc[tc][td][rr]);
      }

#pragma unroll
  for (int tc = 0; tc < 2; ++tc) {
    sq[tc] += __shfl_xor(sq[tc], 16);
    sq[tc] += __shfl_xor(sq[tc], 32);
    sk[tc] += __shfl_xor(sk[tc], 16);
    sk[tc] += __shfl_xor(sk[tc], 32);
  }
  if ((l >> 4) == 0) {
#pragma unroll
    for (int tc = 0; tc < 2; ++tc) {
      atomicAdd(sqq + bh * 32 + tc * 16 + row, sq[tc]);
      atomicAdd(sqk + bh * 32 + tc * 16 + row, sk[tc]);
    }
  }
}

// ---------------------------------------------------------------------------
// K2b: logits = gram/(|q||k|)*temp, row-softmax, fold 1x1 proj:
//   W2[b][o][h*32+d] = sum_c wp[o][h*32+c] * A[c][d]  (bf16 out)
// ---------------------------------------------------------------------------
__global__ __launch_bounds__(256) void k2b_w2(
    const float* __restrict__ gram, const float* __restrict__ sqq,
    const float* __restrict__ sqk, const float* __restrict__ wp,
    const float* __restrict__ temp, u16* __restrict__ W2)
{
  __shared__ float Ls[32][33];
  __shared__ float As[32][33];
  __shared__ float wl[192 * 32];
  __shared__ float nq[32], nk[32];
  const int t = threadIdx.x;
  const int bh = blockIdx.x, b = bh / 6, h = bh % 6;
  const float tmp = temp[h];
  if (t < 32) nq[t] = fmaxf(sqrtf(sqq[bh * 32 + t]), 1e-12f);
  else if (t < 64) nk[t - 32] = fmaxf(sqrtf(sqk[bh * 32 + t - 32]), 1e-12f);
  __syncthreads();
#pragma unroll
  for (int i = 0; i < 4; ++i) {
    int idx = i * 256 + t, c = idx >> 5, d = idx & 31;
    Ls[c][d] = gram[(size_t)bh * 1024 + idx] / (nq[c] * nk[d]) * tmp;
  }
  __syncthreads();
  if (t < 32) {
    float m = -1e30f;
#pragma unroll
    for (int d = 0; d < 32; ++d) m = fmaxf(m, Ls[t][d]);
    float s = 0.f;
#pragma unroll
    for (int d = 0; d < 32; ++d) s += expf(Ls[t][d] - m);
    float inv = 1.0f / s;
#pragma unroll
    for (int d = 0; d < 32; ++d) As[t][d] = expf(Ls[t][d] - m) * inv;
  }
  for (int i = 0; i < 24; ++i) {
    int idx = i * 256 + t, o = idx >> 5, c = idx & 31;
    wl[idx] = wp[o * 192 + h * 32 + c];
  }
  __syncthreads();
  for (int i = 0; i < 24; ++i) {
    int idx = i * 256 + t, o = idx >> 5, d = idx & 31;
    float a = 0.f;
#pragma unroll
    for (int c = 0; c < 32; ++c) a = fmaf(wl[o * 32 + c], As[c][d], a);
    W2[((size_t)(b * 192 + o)) * 192 + h * 32 + d] = f2bf(a);
  }
}

// ---------------------------------------------------------------------------
// K3: out[b][o][n] = sum_c W2[b][o][c] * v[b][c][n], MFMA 16x16x32 bf16.
// v in natural [b][c][n]; per ks-step stage 32x128 tile -> LDS transpose.
// Epilogue: LDS-transpose C so global stores are contiguous float4 runs.
// ---------------------------------------------------------------------------
__global__ __launch_bounds__(256) void k3_gemm(
    const u16* __restrict__ W2, const u16* __restrict__ vnat,
    float* __restrict__ out)
{
  __shared__ __align__(16) u16 b_tile[128 * VTS];
  __shared__ __align__(16) float cout[32 * 132];
  const int t = threadIdx.x, l = t & 63, w = t >> 6;
  const int bx = blockIdx.x;
  const int b  = bx >> 7, nb = bx & 127;
  const int arow = l & 15;
  const int kq8  = (l >> 4) * 8;
  const u16* w2b = W2 + (size_t)b * 192 * 192;
  const u16* vb  = vnat + ((size_t)b * CTOT) * HW;
  const int n0 = nb * 128;

  f32x4 acc[12][2] = {};

  for (int ks = 0; ks < 6; ++ks) {
    if (ks > 0) __syncthreads();
#pragma unroll
    for (int r2 = 0; r2 < 2; ++r2) {
      const int ch   = (t >> 4) + r2 * 16;
      const int nseg = (t & 15) * 8;
      short8 vv = *(const short8*)(vb + (size_t)(ks * 32 + ch) * HW + n0 + nseg);
#pragma unroll
      for (int j = 0; j < 8; ++j) b_tile[(nseg + j) * VTS + ch] = (u16)vv[j];
    }
    __syncthreads();

    short8 bf[2];
#pragma unroll
    for (int nt = 0; nt < 2; ++nt)
      bf[nt] = *(const short8*)&b_tile[(w * 32 + nt * 16 + arow) * VTS + kq8];
#pragma unroll
    for (int ot = 0; ot < 12; ++ot) {
      short8 af = *(const short8*)(w2b + (size_t)(ot * 16 + arow) * 192 + ks * 32 + kq8);
#pragma unroll
      for (int nt = 0; nt < 2; ++nt)
        acc[ot][nt] = __builtin_amdgcn_mfma_f32_16x16x32_bf16(af, bf[nt], acc[ot][nt], 0, 0, 0);
    }
  }

  float* __restrict__ ob = out + ((size_t)b * 192) * 16384;
#pragma unroll
  for (int og = 0; og < 6; ++og) {
    __syncthreads();
#pragma unroll
    for (int oi = 0; oi < 2; ++oi) {
#pragma unroll
      for (int nt = 0; nt < 2; ++nt)
#pragma unroll
        for (int rr = 0; rr < 4; ++rr) {
          const int o_l = oi * 16 + (l >> 4) * 4 + rr;
          const int n_l = w * 32 + nt * 16 + (l & 15);
          cout[o_l * 132 + n_l] = acc[og * 2 + oi][nt][rr];
        }
    }
    __syncthreads();
    const int o_l = t >> 3;
    const int o   = og * 32 + o_l;
#pragma unroll
    for (int c = 0; c < 4; ++c) {
      const int n = (t & 7) * 4 + c * 32;
      float4 v4;
      v4.x = cout[o_l * 132 + n + 0];
      v4.y = cout[o_l * 132 + n + 1];
      v4.z = cout[o_l * 132 + n + 2];
      v4.w = cout[o_l * 132 + n + 3];
      *(float4*)(ob + (size_t)o * 16384 + n0 + n) = v4;
    }
  }
}

// ---------------------------------------------------------------------------
extern "C" void kernel_launch(void* const* d_in, const int* in_sizes, int n_in,
                              void* d_out, int out_size, void* d_ws, size_t ws_size,
                              hipStream_t stream)
{
  const float* x    = (const float*)d_in[0];
  const float* y    = (const float*)d_in[1];
  const float* wdw  = (const float*)d_in[2];
  const float* wp   = (const float*)d_in[3];
  const float* temp = (const float*)d_in[4];

  char* ws = (char*)d_ws;
  const size_t QK = (size_t)NB * CTOT * HW * 2;   // 50,331,648 bytes per tensor
  u16*   qws  = (u16*)(ws);
  u16*   kws  = (u16*)(ws + QK);
  u16*   vws  = (u16*)(ws + 2 * QK);
  float* gram = (float*)(ws + 3 * QK);                  // 196608
  float* sqq  = (float*)(ws + 3 * QK + 196608);         // 6144
  float* sqk  = (float*)(ws + 3 * QK + 196608 + 6144);  // 6144
  u16*   W2   = (u16*)(ws + 3 * QK + 196608 + 12288);   // 8*192*192*2
  float* out  = (float*)d_out;

  hipMemsetAsync(ws + 3 * QK, 0, 208896, stream);
  kconv<<<3072, 256, 0, stream>>>(x, y, wdw, qws, kws, vws);
  k2a_gram<<<768, 256, 0, stream>>>(qws, kws, gram, sqq, sqk);
  k2b_w2<<<48, 256, 0, stream>>>(gram, sqq, sqk, wp, temp, W2);
  k3_gemm<<<1024, 256, 0, stream>>>(W2, vws, out);
}